// Round 10
// baseline (1161.325 us; speedup 1.0000x reference)
//
#include <hip/hip_runtime.h>
#include <math.h>

// AddrNet eval forward: B=524288, D_MODEL=128, HID=16, N_BINS=256, DEPTH=8.
// Round 10: same bit-exact arithmetic contract as PASSING R4-R9 (no-FMA
// separate mul/add roundings, k-ascending sums, bias-after, np-Cephes exp,
// mul-form silu, strict-> argmax). Mapping change vs R9: R=1 row/thread.
// Rationale: weights live in SGPRs (shared per wave), so per-row VALU cost
// is identical for R=1 vs R=2, but R=1 doubles wave count to 8192 = 32/CU
// (100% occupancy) to hide s_load latency. 64-VGPR cap via (256,4) —
// validated toolchain model cap=256/min_waves; R=1 live set ~46 fits.

constexpr int BATCH  = 524288;
constexpr int DM     = 128;
constexpr int H      = 16;
constexpr int NB     = 256;
constexpr int DEPTHN = 8;

constexpr int BLOCK = 256;

__device__ __forceinline__ float np_expf(float x) {
    // Replica of numpy's SIMD float32 exp (Cephes scheme). Explicit FMAs:
    // unaffected by fp-contract settings. MUST stay bit-identical to R4.
    const float LOG2E = 1.442695040888963407f;
    const float C1    = 0.693359375f;
    const float C2    = -2.12194440e-4f;
    float q = rintf(x * LOG2E);
    float r = __builtin_fmaf(q, -C1, x);
    r = __builtin_fmaf(q, -C2, r);
    float p = 1.9875691500E-4f;
    p = __builtin_fmaf(p, r, 1.3981999507E-3f);
    p = __builtin_fmaf(p, r, 8.3334519073E-3f);
    p = __builtin_fmaf(p, r, 4.1665795894E-2f);
    p = __builtin_fmaf(p, r, 1.6666665459E-1f);
    p = __builtin_fmaf(p, r, 5.0000001201E-1f);
    p = __builtin_fmaf(p, r * r, r);
    p = p + 1.0f;
    if (x > 88.72283935546875f)      return INFINITY;
    if (x < -103.97208404541015625f) return 0.0f;
    return ldexpf(p, (int)q);
}

// ---- prep: transpose W_out [16][256] -> ws[0..4095] = WoutT [256][16]
//            and W_mlp [16][16] -> ws[4096..4351] = WmlpT [16][16] ----
__global__ void addrnet_prep_kernel(const float* __restrict__ W_out,
                                    const float* __restrict__ W_mlp,
                                    float* __restrict__ ws) {
    int t = threadIdx.x;                       // 256 threads, 1 block
    for (int i = t; i < NB * H; i += 256) {
        int j = i >> 4, k = i & 15;            // WoutT[j][k] = W_out[k][j]
        ws[j * H + k] = W_out[k * NB + j];
    }
    {
        int i = t >> 4, k = t & 15;            // WmlpT[i][k] = W_mlp[k][i]
        ws[NB * H + i * H + k] = W_mlp[k * H + i];
    }
}

__global__ __launch_bounds__(BLOCK, 4) void addrnet_r10_kernel(
    const float* __restrict__ x,      // [B,128]
    const float* __restrict__ W_in,   // [128,16]
    const float* __restrict__ b_in,   // [16]
    const float* __restrict__ embed,  // [256,16]
    const float* __restrict__ b_mlp,  // [16]
    const float* __restrict__ b_out,  // [256]
    const float* __restrict__ ws,     // WoutT[256][16] ++ WmlpT[16][16]
    int* __restrict__ out)            // [B,8] int32
{
#pragma clang fp contract(off)
    __shared__ __align__(16) float sEmb[NB * H];    // 16 KB, gather target

    for (int i = threadIdx.x; i < NB * H; i += BLOCK) sEmb[i] = embed[i];
    __syncthreads();

    const float* WoutT = ws;               // [j][k], contiguous per bin
    const float* WmlpT = ws + NB * H;      // [i][k]

    const int row = blockIdx.x * BLOCK + threadIdx.x;

    // ---- h = x @ W_in + b_in : mul rounded, then add; k ascending.
    //      W_in rows are wave-uniform global reads (s_load path). ----
    float h[H];
#pragma unroll
    for (int j = 0; j < H; ++j) h[j] = 0.0f;

    const float4* xr = reinterpret_cast<const float4*>(x + (size_t)row * DM);
    for (int k4 = 0; k4 < DM / 4; ++k4) {
        float4 v = xr[k4];
        const float* w0 = &W_in[(k4 * 4 + 0) * H];
        const float* w1 = &W_in[(k4 * 4 + 1) * H];
        const float* w2 = &W_in[(k4 * 4 + 2) * H];
        const float* w3 = &W_in[(k4 * 4 + 3) * H];
#pragma unroll
        for (int j = 0; j < H; ++j) {
            float a = h[j];
            a = a + v.x * w0[j];   // separate mul + add (contract off)
            a = a + v.y * w1[j];
            a = a + v.z * w2[j];
            a = a + v.w * w3[j];
            h[j] = a;
        }
    }
#pragma unroll
    for (int j = 0; j < H; ++j) h[j] = h[j] + b_in[j];

    int* o = out + (size_t)row * DEPTHN;

    for (int d = 0; d < DEPTHN; ++d) {
        // ---- logits = h @ W_out + b_out ; argmax (first-index ties).
        //      Weights via uniform s_load (SGPR operands, no VGPR tile). ----
        float best = -INFINITY;
        int bi = 0;
#pragma unroll 2
        for (int j = 0; j < NB; ++j) {
            const float* wr = &WoutT[j * H];
            float acc = 0.0f;
#pragma unroll
            for (int k = 0; k < H; ++k) acc = acc + h[k] * wr[k];
            acc = acc + b_out[j];
            bool c = acc > best;
            bi   = c ? j   : bi;
            best = c ? acc : best;
        }
        o[d] = bi;

        // ---- h = h + embed[bi] (LDS gather, divergent) ----
        {
            const float4* e = reinterpret_cast<const float4*>(&sEmb[bi * H]);
#pragma unroll
            for (int q4 = 0; q4 < 4; ++q4) {
                float4 ev = e[q4];
                h[q4 * 4 + 0] = h[q4 * 4 + 0] + ev.x;
                h[q4 * 4 + 1] = h[q4 * 4 + 1] + ev.y;
                h[q4 * 4 + 2] = h[q4 * 4 + 2] + ev.z;
                h[q4 * 4 + 3] = h[q4 * 4 + 3] + ev.w;
            }
        }

        // ---- z = h @ W_mlp + b_mlp ; h = z * (1/(1+np_exp(-z))) ----
        float hn[H];
#pragma unroll
        for (int i = 0; i < H; ++i) {
            const float* wr = &WmlpT[i * H];
            float acc = 0.0f;
#pragma unroll
            for (int k = 0; k < H; ++k) acc = acc + h[k] * wr[k];
            acc = acc + b_mlp[i];
            float e = np_expf(-acc);
            float s = 1.0f / (1.0f + e);
            hn[i] = acc * s;
        }
#pragma unroll
        for (int i = 0; i < H; ++i) h[i] = hn[i];
    }
}

extern "C" void kernel_launch(void* const* d_in, const int* in_sizes, int n_in,
                              void* d_out, int out_size, void* d_ws, size_t ws_size,
                              hipStream_t stream) {
    const float* x     = (const float*)d_in[0];
    const float* W_in  = (const float*)d_in[1];
    const float* b_in  = (const float*)d_in[2];
    const float* embed = (const float*)d_in[3];
    const float* W_mlp = (const float*)d_in[4];
    const float* b_mlp = (const float*)d_in[5];
    const float* W_out = (const float*)d_in[6];
    const float* b_out = (const float*)d_in[7];
    int* out  = (int*)d_out;
    float* ws = (float*)d_ws;          // needs (4096+256)*4 = 17.4 KB

    addrnet_prep_kernel<<<1, 256, 0, stream>>>(W_out, W_mlp, ws);

    dim3 grid(BATCH / BLOCK);          // 2048 blocks, 8192 waves
    dim3 block(BLOCK);
    addrnet_r10_kernel<<<grid, block, 0, stream>>>(x, W_in, b_in, embed,
                                                   b_mlp, b_out, ws, out);
}

// Round 11
// 895.897 us; speedup vs baseline: 1.2963x; 1.2963x over previous
//
#include <hip/hip_runtime.h>
#include <math.h>

// AddrNet eval forward: B=524288, D_MODEL=128, HID=16, N_BINS=256, DEPTH=8.
// Round 11: same bit-exact arithmetic contract as PASSING R4-R10 (no-FMA
// separate mul/add roundings, k-ascending sums, bias-after, np-Cephes exp,
// mul-form silu, strict-> argmax). Mapping change: v2f packing along the
// OUTPUT dimension at R=1 (8192 waves):
//   - logits: 2 bins per v2f (weights pair-interleaved by prep kernel ->
//     contiguous 128B uniform s_load per bin-pair, SGPR-pair VOP3P operands)
//   - MLP: 2 outputs per v2f; input layer + h-state: 2 h-elems per v2f
//   Each v2f half is an independent IEEE chain in exact reference order.
// This combines R9's packed busy-time (783us) with R10's 87% duty cycle.

constexpr int BATCH  = 524288;
constexpr int DM     = 128;
constexpr int H      = 16;
constexpr int NB     = 256;
constexpr int DEPTHN = 8;

constexpr int BLOCK = 256;

typedef float v2f __attribute__((ext_vector_type(2)));

__device__ __forceinline__ float np_expf(float x) {
    // Replica of numpy's SIMD float32 exp (Cephes scheme). Explicit FMAs:
    // unaffected by fp-contract settings. MUST stay bit-identical to R4.
    const float LOG2E = 1.442695040888963407f;
    const float C1    = 0.693359375f;
    const float C2    = -2.12194440e-4f;
    float q = rintf(x * LOG2E);
    float r = __builtin_fmaf(q, -C1, x);
    r = __builtin_fmaf(q, -C2, r);
    float p = 1.9875691500E-4f;
    p = __builtin_fmaf(p, r, 1.3981999507E-3f);
    p = __builtin_fmaf(p, r, 8.3334519073E-3f);
    p = __builtin_fmaf(p, r, 4.1665795894E-2f);
    p = __builtin_fmaf(p, r, 1.6666665459E-1f);
    p = __builtin_fmaf(p, r, 5.0000001201E-1f);
    p = __builtin_fmaf(p, r * r, r);
    p = p + 1.0f;
    if (x > 88.72283935546875f)      return INFINITY;
    if (x < -103.97208404541015625f) return 0.0f;
    return ldexpf(p, (int)q);
}

// ---- prep: pair-interleave weights.
//   wsP[p*32 + k*2 + h] = W_out[k][2p+h]   p in [0,128), k in [0,16), h in {0,1}
//   wsM[q*32 + k*2 + h] = W_mlp[k][2q+h]   q in [0,8)    (offset 4096 floats)
__global__ void addrnet_prep_kernel(const float* __restrict__ W_out,
                                    const float* __restrict__ W_mlp,
                                    float* __restrict__ ws) {
    int t = threadIdx.x;                       // 256 threads, 1 block
    for (int i = t; i < NB * H; i += 256) {
        int p = i >> 5, r = i & 31;            // r = k*2+h
        int k = r >> 1, hh = r & 1;
        ws[i] = W_out[k * NB + (2 * p + hh)];
    }
    {
        int i = t;                             // 256 = 8 pairs * 32
        int q = i >> 5, r = i & 31;
        int k = r >> 1, hh = r & 1;
        ws[NB * H + i] = W_mlp[k * H + (2 * q + hh)];
    }
}

__global__ __launch_bounds__(BLOCK, 4) void addrnet_r11_kernel(
    const float* __restrict__ x,      // [B,128]
    const float* __restrict__ W_in,   // [128,16]
    const float* __restrict__ b_in,   // [16]
    const float* __restrict__ embed,  // [256,16]
    const float* __restrict__ b_mlp,  // [16]
    const float* __restrict__ b_out,  // [256]
    const float* __restrict__ ws,     // wsP[128][16] v2f ++ wsM[8][16] v2f
    int* __restrict__ out)            // [B,8] int32
{
#pragma clang fp contract(off)
    __shared__ __align__(16) float sEmb[NB * H];    // 16 KB, gather target

    for (int i = threadIdx.x; i < NB * H; i += BLOCK) sEmb[i] = embed[i];
    __syncthreads();

    const v2f* WP  = reinterpret_cast<const v2f*>(ws);            // [p][k]
    const v2f* WM  = reinterpret_cast<const v2f*>(ws + NB * H);   // [q][k]
    const v2f* BO2 = reinterpret_cast<const v2f*>(b_out);         // pairs
    const v2f* BM2 = reinterpret_cast<const v2f*>(b_mlp);
    const v2f* BI2 = reinterpret_cast<const v2f*>(b_in);

    const int row = blockIdx.x * BLOCK + threadIdx.x;

    // ---- h = x @ W_in + b_in : per-element mul-then-add, k ascending.
    //      h packed as 8 v2f (elems 2j,2j+1); W_in pairs adjacent in memory.
    v2f h2[H / 2];
#pragma unroll
    for (int j = 0; j < H / 2; ++j) h2[j] = (v2f){0.0f, 0.0f};

    const float4* xr = reinterpret_cast<const float4*>(x + (size_t)row * DM);
    for (int k4 = 0; k4 < DM / 4; ++k4) {
        float4 v = xr[k4];
        const v2f* w0 = reinterpret_cast<const v2f*>(&W_in[(k4 * 4 + 0) * H]);
        const v2f* w1 = reinterpret_cast<const v2f*>(&W_in[(k4 * 4 + 1) * H]);
        const v2f* w2 = reinterpret_cast<const v2f*>(&W_in[(k4 * 4 + 2) * H]);
        const v2f* w3 = reinterpret_cast<const v2f*>(&W_in[(k4 * 4 + 3) * H]);
#pragma unroll
        for (int j = 0; j < H / 2; ++j) {
            v2f a = h2[j];
            a = a + w0[j] * v.x;   // pk mul, pk add (separate roundings)
            a = a + w1[j] * v.y;
            a = a + w2[j] * v.z;
            a = a + w3[j] * v.w;
            h2[j] = a;
        }
    }
#pragma unroll
    for (int j = 0; j < H / 2; ++j) h2[j] = h2[j] + BI2[j];

    int* o = out + (size_t)row * DEPTHN;

    for (int d = 0; d < DEPTHN; ++d) {
        // scalar views of h (compile-time halves of h2)
        float hs[H];
#pragma unroll
        for (int j = 0; j < H / 2; ++j) { hs[2 * j] = h2[j].x; hs[2 * j + 1] = h2[j].y; }

        // ---- logits: 2 bins per v2f; argmax sequential (first-index ties) ----
        float best = -INFINITY;
        int bi = 0;
#pragma unroll 2
        for (int p = 0; p < NB / 2; ++p) {
            const v2f* wr = &WP[p * H];        // 16 v2f, contiguous 128 B
            v2f acc = {0.0f, 0.0f};
#pragma unroll
            for (int k = 0; k < H; ++k) acc = acc + wr[k] * hs[k];
            acc = acc + BO2[p];
            float a0 = acc.x, a1 = acc.y;
            bool c0 = a0 > best;
            bi   = c0 ? 2 * p : bi;
            best = c0 ? a0    : best;
            bool c1 = a1 > best;
            bi   = c1 ? 2 * p + 1 : bi;
            best = c1 ? a1        : best;
        }
        o[d] = bi;

        // ---- h = h + embed[bi] (LDS gather, divergent) ----
        {
            const float4* e = reinterpret_cast<const float4*>(&sEmb[bi * H]);
#pragma unroll
            for (int q4 = 0; q4 < 4; ++q4) {
                float4 ev = e[q4];
                h2[q4 * 2 + 0] = h2[q4 * 2 + 0] + (v2f){ev.x, ev.y};
                h2[q4 * 2 + 1] = h2[q4 * 2 + 1] + (v2f){ev.z, ev.w};
            }
#pragma unroll
            for (int j = 0; j < H / 2; ++j) { hs[2 * j] = h2[j].x; hs[2 * j + 1] = h2[j].y; }
        }

        // ---- z = h @ W_mlp + b_mlp ; h = z * (1/(1+np_exp(-z))) ----
        v2f hn2[H / 2];
#pragma unroll
        for (int q = 0; q < H / 2; ++q) {
            const v2f* wr = &WM[q * H];        // 2 MLP outputs per v2f
            v2f acc = {0.0f, 0.0f};
#pragma unroll
            for (int k = 0; k < H; ++k) acc = acc + wr[k] * hs[k];
            acc = acc + BM2[q];
            float z0 = acc.x, z1 = acc.y;
            float e0 = np_expf(-z0);
            float s0 = 1.0f / (1.0f + e0);
            float e1 = np_expf(-z1);
            float s1 = 1.0f / (1.0f + e1);
            hn2[q] = (v2f){z0 * s0, z1 * s1};
        }
#pragma unroll
        for (int q = 0; q < H / 2; ++q) h2[q] = hn2[q];
    }
}

extern "C" void kernel_launch(void* const* d_in, const int* in_sizes, int n_in,
                              void* d_out, int out_size, void* d_ws, size_t ws_size,
                              hipStream_t stream) {
    const float* x     = (const float*)d_in[0];
    const float* W_in  = (const float*)d_in[1];
    const float* b_in  = (const float*)d_in[2];
    const float* embed = (const float*)d_in[3];
    const float* W_mlp = (const float*)d_in[4];
    const float* b_mlp = (const float*)d_in[5];
    const float* W_out = (const float*)d_in[6];
    const float* b_out = (const float*)d_in[7];
    int* out  = (int*)d_out;
    float* ws = (float*)d_ws;          // needs (4096+256)*4 = 17.4 KB

    addrnet_prep_kernel<<<1, 256, 0, stream>>>(W_out, W_mlp, ws);

    dim3 grid(BATCH / BLOCK);          // 2048 blocks, 8192 waves
    dim3 block(BLOCK);
    addrnet_r11_kernel<<<grid, block, 0, stream>>>(x, W_in, b_in, embed,
                                                   b_mlp, b_out, ws, out);
}